// Round 18
// baseline (124.305 us; speedup 1.0000x reference)
//
#include <hip/hip_runtime.h>

#define B_ 2048
#define N_ 200
#define D_ 128
#define NE1 4   // NE+1
#define NN1 3   // NN+1

// ---------------------------------------------------------------------------
// Fused kernel: FOUR batch elements per block, 512 threads, ~55.6 KB LDS.
// Single dispatch; block-local mask detection; PV uses (bb,row-half) waves
// with float2 lanes (full v row per wave-load) + LDS atomicAdd combine;
// softmax normalization folded into PV/attn-write.
// ---------------------------------------------------------------------------
__global__ __launch_bounds__(512, 4) void fused_mha_kernel(
    const float* __restrict__ q, const float* __restrict__ k,
    const float* __restrict__ v, const float* __restrict__ Wq,
    const float* __restrict__ Wk, const float* __restrict__ Wv,
    const float* __restrict__ rel_pri, const float* __restrict__ W_fc,
    const float* __restrict__ b_fc, const float* __restrict__ ln_gamma,
    const float* __restrict__ ln_beta, const int* __restrict__ etype,
    const int* __restrict__ utype, const void* __restrict__ maskp,
    float* __restrict__ y_out, float* __restrict__ attn_out) {
  const int b0 = blockIdx.x * 4;
  const int tid = threadIdx.x;
  const int g = tid & 3, grp = tid >> 2;  // 128 4-lane groups
  const int w = tid >> 6, l = tid & 63;   // 8 waves

  __shared__ __align__(16) float q_s[4][128];
  __shared__ __align__(16) float ehbuf[4][16][136];  // qM; later s[h][e][:]
  __shared__ __align__(16) float p_s[4][4][200];     // Qe overlay; logits->exp
  __shared__ unsigned char et_s[4][200];             // etype | (mask<<4)
  __shared__ unsigned short perm_s[4][200];
  __shared__ unsigned int mword[200];                // block's mask bytes view
  __shared__ int goff_s[4][5];
  __shared__ float pri_s[4][16];                     // pri; later inv[bb][h]
  __shared__ float part_s[4][128];
  __shared__ float red_s[4][8];
  __shared__ int u_s[4];
  __shared__ int sbad;

  float* QeF = &p_s[0][0][0];  // [bb*4+e][j], stride 136

  // ---------------- Phase 0a: mask-storage detection (block-local) ----------------
  if (tid == 0) sbad = 0;
  if (tid < 4) u_s[tid] = utype[b0 + tid];
  {
    int bb = tid >> 7, j = tid & 127;
    q_s[bb][j] = q[(size_t)(b0 + bb) * D_ + j];
  }
  __syncthreads();
  if (tid < 200) {
    unsigned int mw = ((const unsigned int*)maskp)[(size_t)b0 * 50 + tid];
    mword[tid] = mw;
    if (mw > 1u) atomicOr(&sbad, 1);
  }
  __syncthreads();

  // ---------------- Phase 0b: metadata for 4 b ----------------
  const bool isBool = (sbad != 0);
  for (int i = tid; i < 4 * N_; i += 512) {
    int bb = i / 200, n = i - bb * 200;
    int e = etype[(size_t)(b0 + bb) * N_ + n];
    int m;
    if (isBool) {
      int bi = bb * 200 + n;
      m = (mword[bi >> 2] >> ((bi & 3) * 8)) & 255;
    } else {
      m = ((const int*)maskp)[(size_t)(b0 + bb) * N_ + n];
    }
    et_s[bb][n] = (unsigned char)(e | (m ? 16 : 0));
  }
  __syncthreads();

  if (tid < 64) {
    int bb = tid >> 4, e = (tid >> 2) & 3, h = tid & 3;
    pri_s[bb][e * 4 + h] =
        rel_pri[(h * NN1 + u_s[bb]) * NE1 + e] * 0.17677669529663687f;
  }

  // ---- PERM: waves 0-3, one bb each ----
  if (w < 4) {
    const int bb = w;
    int base[5];
    base[0] = 0;
#pragma unroll
    for (int e = 0; e < 4; ++e) {
      int c = 0;
      for (int n0 = 0; n0 < 256; n0 += 64) {
        int n = n0 + l;
        bool act = false;
        if (n < N_) {
          int em = et_s[bb][n];
          act = !(em & 16) && ((em & 3) == e);
        }
        c += __popcll(__ballot(act));
      }
      base[e + 1] = base[e] + c;
    }
    if (l == 0) {
#pragma unroll
      for (int e = 0; e <= 4; ++e) goff_s[bb][e] = base[e];
    }
#pragma unroll
    for (int e = 0; e < 4; ++e) {
      int bpos = base[e];
      for (int n0 = 0; n0 < 256; n0 += 64) {
        int n = n0 + l;
        bool act = false;
        if (n < N_) {
          int em = et_s[bb][n];
          act = !(em & 16) && ((em & 3) == e);
        }
        unsigned long long m = __ballot(act);
        if (act)
          perm_s[bb][bpos + __popcll(m & ((1ull << l) - 1ull))] =
              (unsigned short)n;
        bpos += __popcll(m);
      }
    }
  }

  // ---------------- Phase 1: Qe[bb][e][j], Wq loads shared x4, 8-deep ----------------
  {
#pragma unroll
    for (int pass = 0; pass < 4; ++pass) {
      int idx = pass * 128 + grp;  // 0..511
      int e = idx >> 7, j = idx & 127;
      const float4* wr = (const float4*)(Wq + (size_t)(e * 128 + j) * 128);
      float acc[4] = {0.f, 0.f, 0.f, 0.f};
      float4 wb[8];
#pragma unroll
      for (int t = 0; t < 8; ++t) wb[t] = wr[g + 4 * t];
#pragma unroll
      for (int t = 0; t < 8; ++t) {
        int c = g + 4 * t;
#pragma unroll
        for (int bb = 0; bb < 4; ++bb) {
          float4 qq = ((const float4*)&q_s[bb][0])[c];
          acc[bb] += wb[t].x * qq.x + wb[t].y * qq.y + wb[t].z * qq.z +
                     wb[t].w * qq.w;
        }
      }
#pragma unroll
      for (int bb = 0; bb < 4; ++bb) {
        acc[bb] += __shfl_xor(acc[bb], 1);
        acc[bb] += __shfl_xor(acc[bb], 2);
      }
      if (g == 0) {
#pragma unroll
        for (int bb = 0; bb < 4; ++bb) QeF[(bb * 4 + e) * 136 + j] = acc[bb];
      }
    }
  }
  __syncthreads();

  // ---- Phase 2: qM[bb][eh][d], Wk column loads shared x4 ----
  for (int idx = tid; idx < 16 * 128; idx += 512) {
    int eh = idx >> 7, d = idx & 127;
    int e = eh >> 2, h = eh & 3;
    const float* wkb = Wk + ((size_t)(e * 128 + h * 32)) * 128 + d;
    float acc[4] = {0.f, 0.f, 0.f, 0.f};
#pragma unroll
    for (int i4 = 0; i4 < 8; ++i4) {
      float w0 = wkb[(i4 * 4 + 0) * 128], w1 = wkb[(i4 * 4 + 1) * 128];
      float w2 = wkb[(i4 * 4 + 2) * 128], w3 = wkb[(i4 * 4 + 3) * 128];
#pragma unroll
      for (int bb = 0; bb < 4; ++bb) {
        float4 qe = ((const float4*)(QeF + (bb * 4 + e) * 136))[h * 8 + i4];
        acc[bb] = fmaf(qe.x, w0, acc[bb]);
        acc[bb] = fmaf(qe.y, w1, acc[bb]);
        acc[bb] = fmaf(qe.z, w2, acc[bb]);
        acc[bb] = fmaf(qe.w, w3, acc[bb]);
      }
    }
#pragma unroll
    for (int bb = 0; bb < 4; ++bb)
      ehbuf[bb][eh][d] = acc[bb] * pri_s[bb][eh];
  }
  __syncthreads();

  // ---------------- Phase 3: logits; task id=(bb,n); 8 k-loads in flight ----------------
  for (int pass = 0; pass < 7; ++pass) {
    int id = pass * 128 + grp;
    if (id < 4 * N_) {
      int bb = id / 200, n = id - bb * 200;
      int em = et_s[bb][n];
      if (em & 16) {
        if (g == 0) {
          p_s[bb][0][n] = -1e10f;
          p_s[bb][1][n] = -1e10f;
          p_s[bb][2][n] = -1e10f;
          p_s[bb][3][n] = -1e10f;
        }
      } else {
        const float4* kr =
            (const float4*)(k + ((size_t)(b0 + bb) * N_ + n) * D_);
        float4 kb[8];
#pragma unroll
        for (int t = 0; t < 8; ++t) kb[t] = kr[g + 4 * t];
        const int eh0 = (em & 3) * 4;
        const float4* m0 = (const float4*)&ehbuf[bb][eh0 + 0][0];
        const float4* m1 = (const float4*)&ehbuf[bb][eh0 + 1][0];
        const float4* m2 = (const float4*)&ehbuf[bb][eh0 + 2][0];
        const float4* m3 = (const float4*)&ehbuf[bb][eh0 + 3][0];
        float a0 = 0.f, a1 = 0.f, a2 = 0.f, a3 = 0.f;
#pragma unroll
        for (int t = 0; t < 8; ++t) {
          int c = g + 4 * t;
          float4 x0 = m0[c];
          a0 += kb[t].x * x0.x + kb[t].y * x0.y + kb[t].z * x0.z +
                kb[t].w * x0.w;
          float4 x1 = m1[c];
          a1 += kb[t].x * x1.x + kb[t].y * x1.y + kb[t].z * x1.z +
                kb[t].w * x1.w;
          float4 x2 = m2[c];
          a2 += kb[t].x * x2.x + kb[t].y * x2.y + kb[t].z * x2.z +
                kb[t].w * x2.w;
          float4 x3 = m3[c];
          a3 += kb[t].x * x3.x + kb[t].y * x3.y + kb[t].z * x3.z +
                kb[t].w * x3.w;
        }
        a0 += __shfl_xor(a0, 1);
        a0 += __shfl_xor(a0, 2);
        a1 += __shfl_xor(a1, 1);
        a1 += __shfl_xor(a1, 2);
        a2 += __shfl_xor(a2, 1);
        a2 += __shfl_xor(a2, 2);
        a3 += __shfl_xor(a3, 1);
        a3 += __shfl_xor(a3, 2);
        if (g == 0) {
          p_s[bb][0][n] = a0;
          p_s[bb][1][n] = a1;
          p_s[bb][2][n] = a2;
          p_s[bb][3][n] = a3;
        }
      }
    }
  }
  __syncthreads();

  // ---------------- Phase 4: softmax; keep raw exp; attn = exp*inv; zero ehbuf ----------------
#pragma unroll
  for (int it = 0; it < 2; ++it) {
    int t = w * 2 + it, bb = t >> 2, h = t & 3;
    float mx = -1e30f;
    for (int n = l; n < N_; n += 64) mx = fmaxf(mx, p_s[bb][h][n]);
#pragma unroll
    for (int o = 32; o; o >>= 1) mx = fmaxf(mx, __shfl_xor(mx, o));
    float sum = 0.f;
    for (int n = l; n < N_; n += 64) {
      float e = __expf(p_s[bb][h][n] - mx);  // masked(-1e10) -> exactly 0
      p_s[bb][h][n] = e;                     // keep RAW exp for PV
      sum += e;
    }
#pragma unroll
    for (int o = 32; o; o >>= 1) sum += __shfl_xor(sum, o);
    float inv = 1.f / sum;
    if (l == 0) pri_s[bb][h] = inv;  // pri_s dead after P2; reuse for inv
    for (int n = l; n < N_; n += 64)
      attn_out[((size_t)h * B_ + (b0 + bb)) * N_ + n] = p_s[bb][h][n] * inv;
    // zero this (bb,h)'s s-rows for PV's atomic accumulation
#pragma unroll
    for (int e = 0; e < 4; ++e) {
      ehbuf[bb][e * 4 + h][l] = 0.f;
      ehbuf[bb][e * 4 + h][64 + l] = 0.f;
    }
  }
  __syncthreads();

  // ---------------- Phase 5: PV; wave=(bb,row-half); float2 lanes ----------------
  // Each wave covers full d (lane d = 2l..2l+1) over alternate perm entries;
  // the two row-half waves combine via LDS atomicAdd onto zeroed s-rows
  // (exactly 2 contributors per location -> deterministic).
  {
    const int bb = w >> 1, rh = w & 1;
    const float2* vb2 = (const float2*)(v + (size_t)(b0 + bb) * N_ * D_);
    float inv_h[4];
#pragma unroll
    for (int h = 0; h < 4; ++h) inv_h[h] = pri_s[bb][h];
#pragma unroll
    for (int e = 0; e < 4; ++e) {
      const int j0 = goff_s[bb][e], j1 = goff_s[bb][e + 1];
      float2 acc0 = {0.f, 0.f}, acc1 = {0.f, 0.f};
      float2 acc2 = {0.f, 0.f}, acc3 = {0.f, 0.f};
      for (int j = j0 + rh; j < j1; j += 16) {  // 8 entries, step 2
        int nn[8];
        float okf[8];
        float2 vv[8];
#pragma unroll
        for (int u = 0; u < 8; ++u) {
          int jj = j + 2 * u;
          bool ok = jj < j1;
          nn[u] = ok ? (int)perm_s[bb][jj] : (int)perm_s[bb][j0];
          okf[u] = ok ? 1.f : 0.f;
        }
#pragma unroll
        for (int u = 0; u < 8; ++u) vv[u] = vb2[nn[u] * 64 + l];
#pragma unroll
        for (int u = 0; u < 8; ++u) {
          float p0 = p_s[bb][0][nn[u]] * okf[u];
          acc0.x = fmaf(p0, vv[u].x, acc0.x);
          acc0.y = fmaf(p0, vv[u].y, acc0.y);
          float p1 = p_s[bb][1][nn[u]] * okf[u];
          acc1.x = fmaf(p1, vv[u].x, acc1.x);
          acc1.y = fmaf(p1, vv[u].y, acc1.y);
          float p2 = p_s[bb][2][nn[u]] * okf[u];
          acc2.x = fmaf(p2, vv[u].x, acc2.x);
          acc2.y = fmaf(p2, vv[u].y, acc2.y);
          float p3 = p_s[bb][3][nn[u]] * okf[u];
          acc3.x = fmaf(p3, vv[u].x, acc3.x);
          acc3.y = fmaf(p3, vv[u].y, acc3.y);
        }
      }
      atomicAdd(&ehbuf[bb][e * 4 + 0][2 * l], acc0.x * inv_h[0]);
      atomicAdd(&ehbuf[bb][e * 4 + 0][2 * l + 1], acc0.y * inv_h[0]);
      atomicAdd(&ehbuf[bb][e * 4 + 1][2 * l], acc1.x * inv_h[1]);
      atomicAdd(&ehbuf[bb][e * 4 + 1][2 * l + 1], acc1.y * inv_h[1]);
      atomicAdd(&ehbuf[bb][e * 4 + 2][2 * l], acc2.x * inv_h[2]);
      atomicAdd(&ehbuf[bb][e * 4 + 2][2 * l + 1], acc2.y * inv_h[2]);
      atomicAdd(&ehbuf[bb][e * 4 + 3][2 * l], acc3.x * inv_h[3]);
      atomicAdd(&ehbuf[bb][e * 4 + 3][2 * l + 1], acc3.y * inv_h[3]);
    }
  }
  __syncthreads();

  // ---------------- Phase 6: Wv contract; loads shared x4, 8-deep ----------------
  {
    int row = grp, hh = row >> 5;
    float acc[4] = {0.f, 0.f, 0.f, 0.f};
#pragma unroll
    for (int e = 0; e < 4; ++e) {
      const float4* wr = (const float4*)(Wv + ((size_t)e * 128 + row) * 128);
      float4 wb[8];
#pragma unroll
      for (int t = 0; t < 8; ++t) wb[t] = wr[g + 4 * t];
#pragma unroll
      for (int t = 0; t < 8; ++t) {
        int c = g + 4 * t;
#pragma unroll
        for (int bb = 0; bb < 4; ++bb) {
          float4 sv = ((const float4*)&ehbuf[bb][e * 4 + hh][0])[c];
          acc[bb] += wb[t].x * sv.x + wb[t].y * sv.y + wb[t].z * sv.z +
                     wb[t].w * sv.w;
        }
      }
    }
#pragma unroll
    for (int bb = 0; bb < 4; ++bb) {
      acc[bb] += __shfl_xor(acc[bb], 1);
      acc[bb] += __shfl_xor(acc[bb], 2);
    }
    if (g == 0) {
#pragma unroll
      for (int bb = 0; bb < 4; ++bb) part_s[bb][row] = acc[bb];
    }
  }
  __syncthreads();

  // ---------------- Phase 7: FC (one (bb,j) per thread) + residual + LN ----------------
  {
    const int bb = tid >> 7, j = tid & 127;
    const float* wf = W_fc + ((size_t)u_s[bb] * 128) * 128 + j;
    float acc = 0.f;
    for (int r0 = 0; r0 < 128; r0 += 8) {
      float wv[8], ov[8];
#pragma unroll
      for (int u = 0; u < 8; ++u) wv[u] = wf[(r0 + u) * 128];
#pragma unroll
      for (int u = 0; u < 8; ++u) ov[u] = part_s[bb][r0 + u];
#pragma unroll
      for (int u = 0; u < 8; ++u) acc = fmaf(ov[u], wv[u], acc);
    }
    float x = acc + b_fc[u_s[bb] * 128 + j] + q_s[bb][j];

    float s1 = x, s2 = x * x;
#pragma unroll
    for (int o = 32; o; o >>= 1) {
      s1 += __shfl_xor(s1, o);
      s2 += __shfl_xor(s2, o);
    }
    const int half = (tid >> 6) & 1;
    if (l == 0) {
      red_s[bb][half] = s1;
      red_s[bb][4 + half] = s2;
    }
    __syncthreads();
    float t1 = red_s[bb][0] + red_s[bb][1];
    float t2 = red_s[bb][4] + red_s[bb][5];
    float mu = t1 * (1.f / 128.f);
    float var = t2 * (1.f / 128.f) - mu * mu;
    float yv = (x - mu) * rsqrtf(var + 1e-5f) * ln_gamma[j] + ln_beta[j];
    y_out[(size_t)(b0 + bb) * 128 + j] = yv;
  }
}

extern "C" void kernel_launch(void* const* d_in, const int* in_sizes, int n_in,
                              void* d_out, int out_size, void* d_ws,
                              size_t ws_size, hipStream_t stream) {
  const float* q = (const float*)d_in[0];
  const float* k = (const float*)d_in[1];
  const float* v = (const float*)d_in[2];
  const float* Wq = (const float*)d_in[3];
  const float* Wk = (const float*)d_in[4];
  const float* Wv = (const float*)d_in[5];
  const float* rp = (const float*)d_in[6];
  const float* Wf = (const float*)d_in[7];
  const float* bf = (const float*)d_in[8];
  const float* g = (const float*)d_in[9];
  const float* be = (const float*)d_in[10];
  const int* et = (const int*)d_in[11];
  const int* ut = (const int*)d_in[12];
  const void* mask = d_in[13];

  float* y = (float*)d_out;
  float* attn = y + (size_t)B_ * D_;

  fused_mha_kernel<<<B_ / 4, 512, 0, stream>>>(q, k, v, Wq, Wk, Wv, rp, Wf, bf,
                                               g, be, et, ut, mask, y, attn);
}

// Round 19
// 98.331 us; speedup vs baseline: 1.2642x; 1.2642x over previous
//
#include <hip/hip_runtime.h>

#define B_ 2048
#define N_ 200
#define D_ 128
#define NE1 4   // NE+1
#define NN1 3   // NN+1

// ---------------------------------------------------------------------------
// Fused kernel: FOUR batch elements per block, 512 threads, ~55.6 KB LDS.
// Single dispatch; block-local mask detection; PV restructured as
// (bb, d-half) waves so each v row is fetched once (was 4x).
// Verified optimum (R16): 98.2 us.
// ---------------------------------------------------------------------------
__global__ __launch_bounds__(512, 4) void fused_mha_kernel(
    const float* __restrict__ q, const float* __restrict__ k,
    const float* __restrict__ v, const float* __restrict__ Wq,
    const float* __restrict__ Wk, const float* __restrict__ Wv,
    const float* __restrict__ rel_pri, const float* __restrict__ W_fc,
    const float* __restrict__ b_fc, const float* __restrict__ ln_gamma,
    const float* __restrict__ ln_beta, const int* __restrict__ etype,
    const int* __restrict__ utype, const void* __restrict__ maskp,
    float* __restrict__ y_out, float* __restrict__ attn_out) {
  const int b0 = blockIdx.x * 4;
  const int tid = threadIdx.x;
  const int g = tid & 3, grp = tid >> 2;  // 128 4-lane groups
  const int w = tid >> 6, l = tid & 63;   // 8 waves

  __shared__ __align__(16) float q_s[4][128];
  __shared__ __align__(16) float ehbuf[4][16][136];  // qM; later s[h][e][:]
  __shared__ __align__(16) float p_s[4][4][200];     // Qe overlay; logits->probs
  __shared__ unsigned char et_s[4][200];             // etype | (mask<<4)
  __shared__ unsigned short perm_s[4][200];
  __shared__ unsigned int mword[200];                // block's mask bytes view
  __shared__ int goff_s[4][5];
  __shared__ float pri_s[4][16];
  __shared__ float part_s[4][128];
  __shared__ float red_s[4][8];
  __shared__ int u_s[4];
  __shared__ int sbad;

  float* QeF = &p_s[0][0][0];  // [bb*4+e][j], stride 136

  // ---------------- Phase 0a: mask-storage detection (block-local) ----------------
  if (tid == 0) sbad = 0;
  if (tid < 4) u_s[tid] = utype[b0 + tid];
  {
    int bb = tid >> 7, j = tid & 127;
    q_s[bb][j] = q[(size_t)(b0 + bb) * D_ + j];
  }
  __syncthreads();
  if (tid < 200) {
    unsigned int mw = ((const unsigned int*)maskp)[(size_t)b0 * 50 + tid];
    mword[tid] = mw;
    if (mw > 1u) atomicOr(&sbad, 1);
  }
  __syncthreads();

  // ---------------- Phase 0b: metadata for 4 b ----------------
  const bool isBool = (sbad != 0);
  for (int i = tid; i < 4 * N_; i += 512) {
    int bb = i / 200, n = i - bb * 200;
    int e = etype[(size_t)(b0 + bb) * N_ + n];
    int m;
    if (isBool) {
      int bi = bb * 200 + n;
      m = (mword[bi >> 2] >> ((bi & 3) * 8)) & 255;
    } else {
      m = ((const int*)maskp)[(size_t)(b0 + bb) * N_ + n];
    }
    et_s[bb][n] = (unsigned char)(e | (m ? 16 : 0));
  }
  __syncthreads();

  if (tid < 64) {
    int bb = tid >> 4, e = (tid >> 2) & 3, h = tid & 3;
    pri_s[bb][e * 4 + h] =
        rel_pri[(h * NN1 + u_s[bb]) * NE1 + e] * 0.17677669529663687f;
  }

  // ---- PERM: waves 0-3, one bb each ----
  if (w < 4) {
    const int bb = w;
    int base[5];
    base[0] = 0;
#pragma unroll
    for (int e = 0; e < 4; ++e) {
      int c = 0;
      for (int n0 = 0; n0 < 256; n0 += 64) {
        int n = n0 + l;
        bool act = false;
        if (n < N_) {
          int em = et_s[bb][n];
          act = !(em & 16) && ((em & 3) == e);
        }
        c += __popcll(__ballot(act));
      }
      base[e + 1] = base[e] + c;
    }
    if (l == 0) {
#pragma unroll
      for (int e = 0; e <= 4; ++e) goff_s[bb][e] = base[e];
    }
#pragma unroll
    for (int e = 0; e < 4; ++e) {
      int bpos = base[e];
      for (int n0 = 0; n0 < 256; n0 += 64) {
        int n = n0 + l;
        bool act = false;
        if (n < N_) {
          int em = et_s[bb][n];
          act = !(em & 16) && ((em & 3) == e);
        }
        unsigned long long m = __ballot(act);
        if (act)
          perm_s[bb][bpos + __popcll(m & ((1ull << l) - 1ull))] =
              (unsigned short)n;
        bpos += __popcll(m);
      }
    }
  }

  // ---------------- Phase 1: Qe[bb][e][j], Wq loads shared x4, 8-deep ----------------
  {
#pragma unroll
    for (int pass = 0; pass < 4; ++pass) {
      int idx = pass * 128 + grp;  // 0..511
      int e = idx >> 7, j = idx & 127;
      const float4* wr = (const float4*)(Wq + (size_t)(e * 128 + j) * 128);
      float acc[4] = {0.f, 0.f, 0.f, 0.f};
      float4 wb[8];
#pragma unroll
      for (int t = 0; t < 8; ++t) wb[t] = wr[g + 4 * t];
#pragma unroll
      for (int t = 0; t < 8; ++t) {
        int c = g + 4 * t;
#pragma unroll
        for (int bb = 0; bb < 4; ++bb) {
          float4 qq = ((const float4*)&q_s[bb][0])[c];
          acc[bb] += wb[t].x * qq.x + wb[t].y * qq.y + wb[t].z * qq.z +
                     wb[t].w * qq.w;
        }
      }
#pragma unroll
      for (int bb = 0; bb < 4; ++bb) {
        acc[bb] += __shfl_xor(acc[bb], 1);
        acc[bb] += __shfl_xor(acc[bb], 2);
      }
      if (g == 0) {
#pragma unroll
        for (int bb = 0; bb < 4; ++bb) QeF[(bb * 4 + e) * 136 + j] = acc[bb];
      }
    }
  }
  __syncthreads();

  // ---- Phase 2: qM[bb][eh][d], Wk column loads shared x4 ----
  for (int idx = tid; idx < 16 * 128; idx += 512) {
    int eh = idx >> 7, d = idx & 127;
    int e = eh >> 2, h = eh & 3;
    const float* wkb = Wk + ((size_t)(e * 128 + h * 32)) * 128 + d;
    float acc[4] = {0.f, 0.f, 0.f, 0.f};
#pragma unroll
    for (int i4 = 0; i4 < 8; ++i4) {
      float w0 = wkb[(i4 * 4 + 0) * 128], w1 = wkb[(i4 * 4 + 1) * 128];
      float w2 = wkb[(i4 * 4 + 2) * 128], w3 = wkb[(i4 * 4 + 3) * 128];
#pragma unroll
      for (int bb = 0; bb < 4; ++bb) {
        float4 qe = ((const float4*)(QeF + (bb * 4 + e) * 136))[h * 8 + i4];
        acc[bb] = fmaf(qe.x, w0, acc[bb]);
        acc[bb] = fmaf(qe.y, w1, acc[bb]);
        acc[bb] = fmaf(qe.z, w2, acc[bb]);
        acc[bb] = fmaf(qe.w, w3, acc[bb]);
      }
    }
#pragma unroll
    for (int bb = 0; bb < 4; ++bb)
      ehbuf[bb][eh][d] = acc[bb] * pri_s[bb][eh];
  }
  __syncthreads();

  // ---------------- Phase 3: logits; task id=(bb,n); 8 k-loads in flight ----------------
  for (int pass = 0; pass < 7; ++pass) {
    int id = pass * 128 + grp;
    if (id < 4 * N_) {
      int bb = id / 200, n = id - bb * 200;
      int em = et_s[bb][n];
      if (em & 16) {
        if (g == 0) {
          p_s[bb][0][n] = -1e10f;
          p_s[bb][1][n] = -1e10f;
          p_s[bb][2][n] = -1e10f;
          p_s[bb][3][n] = -1e10f;
        }
      } else {
        const float4* kr =
            (const float4*)(k + ((size_t)(b0 + bb) * N_ + n) * D_);
        float4 kb[8];
#pragma unroll
        for (int t = 0; t < 8; ++t) kb[t] = kr[g + 4 * t];
        const int eh0 = (em & 3) * 4;
        const float4* m0 = (const float4*)&ehbuf[bb][eh0 + 0][0];
        const float4* m1 = (const float4*)&ehbuf[bb][eh0 + 1][0];
        const float4* m2 = (const float4*)&ehbuf[bb][eh0 + 2][0];
        const float4* m3 = (const float4*)&ehbuf[bb][eh0 + 3][0];
        float a0 = 0.f, a1 = 0.f, a2 = 0.f, a3 = 0.f;
#pragma unroll
        for (int t = 0; t < 8; ++t) {
          int c = g + 4 * t;
          float4 x0 = m0[c];
          a0 += kb[t].x * x0.x + kb[t].y * x0.y + kb[t].z * x0.z +
                kb[t].w * x0.w;
          float4 x1 = m1[c];
          a1 += kb[t].x * x1.x + kb[t].y * x1.y + kb[t].z * x1.z +
                kb[t].w * x1.w;
          float4 x2 = m2[c];
          a2 += kb[t].x * x2.x + kb[t].y * x2.y + kb[t].z * x2.z +
                kb[t].w * x2.w;
          float4 x3 = m3[c];
          a3 += kb[t].x * x3.x + kb[t].y * x3.y + kb[t].z * x3.z +
                kb[t].w * x3.w;
        }
        a0 += __shfl_xor(a0, 1);
        a0 += __shfl_xor(a0, 2);
        a1 += __shfl_xor(a1, 1);
        a1 += __shfl_xor(a1, 2);
        a2 += __shfl_xor(a2, 1);
        a2 += __shfl_xor(a2, 2);
        a3 += __shfl_xor(a3, 1);
        a3 += __shfl_xor(a3, 2);
        if (g == 0) {
          p_s[bb][0][n] = a0;
          p_s[bb][1][n] = a1;
          p_s[bb][2][n] = a2;
          p_s[bb][3][n] = a3;
        }
      }
    }
  }
  __syncthreads();

  // ---------------- Phase 4: softmax; wave task t=(bb,h) ----------------
#pragma unroll
  for (int it = 0; it < 2; ++it) {
    int t = w * 2 + it, bb = t >> 2, h = t & 3;
    float mx = -1e30f;
    for (int n = l; n < N_; n += 64) mx = fmaxf(mx, p_s[bb][h][n]);
#pragma unroll
    for (int o = 32; o; o >>= 1) mx = fmaxf(mx, __shfl_xor(mx, o));
    float sum = 0.f;
    for (int n = l; n < N_; n += 64) {
      float e = __expf(p_s[bb][h][n] - mx);
      p_s[bb][h][n] = e;
      sum += e;
    }
#pragma unroll
    for (int o = 32; o; o >>= 1) sum += __shfl_xor(sum, o);
    float inv = 1.f / sum;
    for (int n = l; n < N_; n += 64) {
      float pp = p_s[bb][h][n] * inv;
      p_s[bb][h][n] = pp;
      attn_out[((size_t)h * B_ + (b0 + bb)) * N_ + n] = pp;
    }
  }
  __syncthreads();

  // ---------------- Phase 5: PV; wave=(bb, d-half); v row fetched once ----------------
  {
    const int bb = w >> 1, dh = w & 1;
    const int d = dh * 64 + l;
    const float* vb = v + (size_t)(b0 + bb) * N_ * D_ + d;
    float acc[4][4];  // [h][e], statically indexed
#pragma unroll
    for (int h = 0; h < 4; ++h)
#pragma unroll
      for (int e = 0; e < 4; ++e) acc[h][e] = 0.f;
#pragma unroll
    for (int e = 0; e < 4; ++e) {
      const int j0 = goff_s[bb][e], j1 = goff_s[bb][e + 1];
      for (int j = j0; j < j1; j += 8) {
        int nn[8];
        float okf[8];
        float vv[8];
#pragma unroll
        for (int u = 0; u < 8; ++u) {
          bool ok = (j + u) < j1;
          nn[u] = ok ? (int)perm_s[bb][j + u] : (int)perm_s[bb][j0];
          okf[u] = ok ? 1.f : 0.f;
        }
#pragma unroll
        for (int u = 0; u < 8; ++u) vv[u] = vb[nn[u] * D_];
#pragma unroll
        for (int u = 0; u < 8; ++u) {
          float vx = vv[u] * okf[u];
          acc[0][e] = fmaf(p_s[bb][0][nn[u]], vx, acc[0][e]);
          acc[1][e] = fmaf(p_s[bb][1][nn[u]], vx, acc[1][e]);
          acc[2][e] = fmaf(p_s[bb][2][nn[u]], vx, acc[2][e]);
          acc[3][e] = fmaf(p_s[bb][3][nn[u]], vx, acc[3][e]);
        }
      }
#pragma unroll
      for (int h = 0; h < 4; ++h) ehbuf[bb][e * 4 + h][d] = acc[h][e];
    }
  }
  __syncthreads();

  // ---------------- Phase 6: Wv contract; loads shared x4, 8-deep ----------------
  {
    int row = grp, hh = row >> 5;
    float acc[4] = {0.f, 0.f, 0.f, 0.f};
#pragma unroll
    for (int e = 0; e < 4; ++e) {
      const float4* wr = (const float4*)(Wv + ((size_t)e * 128 + row) * 128);
      float4 wb[8];
#pragma unroll
      for (int t = 0; t < 8; ++t) wb[t] = wr[g + 4 * t];
#pragma unroll
      for (int t = 0; t < 8; ++t) {
        int c = g + 4 * t;
#pragma unroll
        for (int bb = 0; bb < 4; ++bb) {
          float4 sv = ((const float4*)&ehbuf[bb][e * 4 + hh][0])[c];
          acc[bb] += wb[t].x * sv.x + wb[t].y * sv.y + wb[t].z * sv.z +
                     wb[t].w * sv.w;
        }
      }
    }
#pragma unroll
    for (int bb = 0; bb < 4; ++bb) {
      acc[bb] += __shfl_xor(acc[bb], 1);
      acc[bb] += __shfl_xor(acc[bb], 2);
    }
    if (g == 0) {
#pragma unroll
      for (int bb = 0; bb < 4; ++bb) part_s[bb][row] = acc[bb];
    }
  }
  __syncthreads();

  // ---------------- Phase 7: FC (one (bb,j) per thread) + residual + LN ----------------
  {
    const int bb = tid >> 7, j = tid & 127;
    const float* wf = W_fc + ((size_t)u_s[bb] * 128) * 128 + j;
    float acc = 0.f;
    for (int r0 = 0; r0 < 128; r0 += 8) {
      float wv[8], ov[8];
#pragma unroll
      for (int u = 0; u < 8; ++u) wv[u] = wf[(r0 + u) * 128];
#pragma unroll
      for (int u = 0; u < 8; ++u) ov[u] = part_s[bb][r0 + u];
#pragma unroll
      for (int u = 0; u < 8; ++u) acc = fmaf(ov[u], wv[u], acc);
    }
    float x = acc + b_fc[u_s[bb] * 128 + j] + q_s[bb][j];

    float s1 = x, s2 = x * x;
#pragma unroll
    for (int o = 32; o; o >>= 1) {
      s1 += __shfl_xor(s1, o);
      s2 += __shfl_xor(s2, o);
    }
    const int half = (tid >> 6) & 1;
    if (l == 0) {
      red_s[bb][half] = s1;
      red_s[bb][4 + half] = s2;
    }
    __syncthreads();
    float t1 = red_s[bb][0] + red_s[bb][1];
    float t2 = red_s[bb][4] + red_s[bb][5];
    float mu = t1 * (1.f / 128.f);
    float var = t2 * (1.f / 128.f) - mu * mu;
    float yv = (x - mu) * rsqrtf(var + 1e-5f) * ln_gamma[j] + ln_beta[j];
    y_out[(size_t)(b0 + bb) * 128 + j] = yv;
  }
}

extern "C" void kernel_launch(void* const* d_in, const int* in_sizes, int n_in,
                              void* d_out, int out_size, void* d_ws,
                              size_t ws_size, hipStream_t stream) {
  const float* q = (const float*)d_in[0];
  const float* k = (const float*)d_in[1];
  const float* v = (const float*)d_in[2];
  const float* Wq = (const float*)d_in[3];
  const float* Wk = (const float*)d_in[4];
  const float* Wv = (const float*)d_in[5];
  const float* rp = (const float*)d_in[6];
  const float* Wf = (const float*)d_in[7];
  const float* bf = (const float*)d_in[8];
  const float* g = (const float*)d_in[9];
  const float* be = (const float*)d_in[10];
  const int* et = (const int*)d_in[11];
  const int* ut = (const int*)d_in[12];
  const void* mask = d_in[13];

  float* y = (float*)d_out;
  float* attn = y + (size_t)B_ * D_;

  fused_mha_kernel<<<B_ / 4, 512, 0, stream>>>(q, k, v, Wq, Wk, Wv, rp, Wf, bf,
                                               g, be, et, ut, mask, y, attn);
}

// Round 20
// 97.410 us; speedup vs baseline: 1.2761x; 1.0095x over previous
//
#include <hip/hip_runtime.h>

#define B_ 2048
#define N_ 200
#define D_ 128
#define NE1 4   // NE+1
#define NN1 3   // NN+1

// ---------------------------------------------------------------------------
// Fused kernel: FOUR batch elements per block, 512 threads, ~55.6 KB LDS.
// Single dispatch; block-local mask detection. PV: wave=(bb, e-pair), lane
// holds float2 -> one 512B wave-load per v row, half the serialized batch
// chain of R16, exclusive s[h][e] ownership (no atomics).
// ---------------------------------------------------------------------------
__global__ __launch_bounds__(512, 4) void fused_mha_kernel(
    const float* __restrict__ q, const float* __restrict__ k,
    const float* __restrict__ v, const float* __restrict__ Wq,
    const float* __restrict__ Wk, const float* __restrict__ Wv,
    const float* __restrict__ rel_pri, const float* __restrict__ W_fc,
    const float* __restrict__ b_fc, const float* __restrict__ ln_gamma,
    const float* __restrict__ ln_beta, const int* __restrict__ etype,
    const int* __restrict__ utype, const void* __restrict__ maskp,
    float* __restrict__ y_out, float* __restrict__ attn_out) {
  const int b0 = blockIdx.x * 4;
  const int tid = threadIdx.x;
  const int g = tid & 3, grp = tid >> 2;  // 128 4-lane groups
  const int w = tid >> 6, l = tid & 63;   // 8 waves

  __shared__ __align__(16) float q_s[4][128];
  __shared__ __align__(16) float ehbuf[4][16][136];  // qM; later s[h][e][:]
  __shared__ __align__(16) float p_s[4][4][200];     // Qe overlay; logits->probs
  __shared__ unsigned char et_s[4][200];             // etype | (mask<<4)
  __shared__ unsigned short perm_s[4][200];
  __shared__ unsigned int mword[200];                // block's mask bytes view
  __shared__ int goff_s[4][5];
  __shared__ float pri_s[4][16];
  __shared__ float part_s[4][128];
  __shared__ float red_s[4][8];
  __shared__ int u_s[4];
  __shared__ int sbad;

  float* QeF = &p_s[0][0][0];  // [bb*4+e][j], stride 136

  // ---------------- Phase 0a: mask-storage detection (block-local) ----------------
  if (tid == 0) sbad = 0;
  if (tid < 4) u_s[tid] = utype[b0 + tid];
  {
    int bb = tid >> 7, j = tid & 127;
    q_s[bb][j] = q[(size_t)(b0 + bb) * D_ + j];
  }
  __syncthreads();
  if (tid < 200) {
    unsigned int mw = ((const unsigned int*)maskp)[(size_t)b0 * 50 + tid];
    mword[tid] = mw;
    if (mw > 1u) atomicOr(&sbad, 1);
  }
  __syncthreads();

  // ---------------- Phase 0b: metadata for 4 b ----------------
  const bool isBool = (sbad != 0);
  for (int i = tid; i < 4 * N_; i += 512) {
    int bb = i / 200, n = i - bb * 200;
    int e = etype[(size_t)(b0 + bb) * N_ + n];
    int m;
    if (isBool) {
      int bi = bb * 200 + n;
      m = (mword[bi >> 2] >> ((bi & 3) * 8)) & 255;
    } else {
      m = ((const int*)maskp)[(size_t)(b0 + bb) * N_ + n];
    }
    et_s[bb][n] = (unsigned char)(e | (m ? 16 : 0));
  }
  __syncthreads();

  if (tid < 64) {
    int bb = tid >> 4, e = (tid >> 2) & 3, h = tid & 3;
    pri_s[bb][e * 4 + h] =
        rel_pri[(h * NN1 + u_s[bb]) * NE1 + e] * 0.17677669529663687f;
  }

  // ---- PERM: waves 0-3, one bb each ----
  if (w < 4) {
    const int bb = w;
    int base[5];
    base[0] = 0;
#pragma unroll
    for (int e = 0; e < 4; ++e) {
      int c = 0;
      for (int n0 = 0; n0 < 256; n0 += 64) {
        int n = n0 + l;
        bool act = false;
        if (n < N_) {
          int em = et_s[bb][n];
          act = !(em & 16) && ((em & 3) == e);
        }
        c += __popcll(__ballot(act));
      }
      base[e + 1] = base[e] + c;
    }
    if (l == 0) {
#pragma unroll
      for (int e = 0; e <= 4; ++e) goff_s[bb][e] = base[e];
    }
#pragma unroll
    for (int e = 0; e < 4; ++e) {
      int bpos = base[e];
      for (int n0 = 0; n0 < 256; n0 += 64) {
        int n = n0 + l;
        bool act = false;
        if (n < N_) {
          int em = et_s[bb][n];
          act = !(em & 16) && ((em & 3) == e);
        }
        unsigned long long m = __ballot(act);
        if (act)
          perm_s[bb][bpos + __popcll(m & ((1ull << l) - 1ull))] =
              (unsigned short)n;
        bpos += __popcll(m);
      }
    }
  }

  // ---------------- Phase 1: Qe[bb][e][j], Wq loads shared x4, 8-deep ----------------
  {
#pragma unroll
    for (int pass = 0; pass < 4; ++pass) {
      int idx = pass * 128 + grp;  // 0..511
      int e = idx >> 7, j = idx & 127;
      const float4* wr = (const float4*)(Wq + (size_t)(e * 128 + j) * 128);
      float acc[4] = {0.f, 0.f, 0.f, 0.f};
      float4 wb[8];
#pragma unroll
      for (int t = 0; t < 8; ++t) wb[t] = wr[g + 4 * t];
#pragma unroll
      for (int t = 0; t < 8; ++t) {
        int c = g + 4 * t;
#pragma unroll
        for (int bb = 0; bb < 4; ++bb) {
          float4 qq = ((const float4*)&q_s[bb][0])[c];
          acc[bb] += wb[t].x * qq.x + wb[t].y * qq.y + wb[t].z * qq.z +
                     wb[t].w * qq.w;
        }
      }
#pragma unroll
      for (int bb = 0; bb < 4; ++bb) {
        acc[bb] += __shfl_xor(acc[bb], 1);
        acc[bb] += __shfl_xor(acc[bb], 2);
      }
      if (g == 0) {
#pragma unroll
        for (int bb = 0; bb < 4; ++bb) QeF[(bb * 4 + e) * 136 + j] = acc[bb];
      }
    }
  }
  __syncthreads();

  // ---- Phase 2: qM[bb][eh][d], Wk column loads shared x4 ----
  for (int idx = tid; idx < 16 * 128; idx += 512) {
    int eh = idx >> 7, d = idx & 127;
    int e = eh >> 2, h = eh & 3;
    const float* wkb = Wk + ((size_t)(e * 128 + h * 32)) * 128 + d;
    float acc[4] = {0.f, 0.f, 0.f, 0.f};
#pragma unroll
    for (int i4 = 0; i4 < 8; ++i4) {
      float w0 = wkb[(i4 * 4 + 0) * 128], w1 = wkb[(i4 * 4 + 1) * 128];
      float w2 = wkb[(i4 * 4 + 2) * 128], w3 = wkb[(i4 * 4 + 3) * 128];
#pragma unroll
      for (int bb = 0; bb < 4; ++bb) {
        float4 qe = ((const float4*)(QeF + (bb * 4 + e) * 136))[h * 8 + i4];
        acc[bb] = fmaf(qe.x, w0, acc[bb]);
        acc[bb] = fmaf(qe.y, w1, acc[bb]);
        acc[bb] = fmaf(qe.z, w2, acc[bb]);
        acc[bb] = fmaf(qe.w, w3, acc[bb]);
      }
    }
#pragma unroll
    for (int bb = 0; bb < 4; ++bb)
      ehbuf[bb][eh][d] = acc[bb] * pri_s[bb][eh];
  }
  __syncthreads();

  // ---------------- Phase 3: logits; task id=(bb,n); 8 k-loads in flight ----------------
  for (int pass = 0; pass < 7; ++pass) {
    int id = pass * 128 + grp;
    if (id < 4 * N_) {
      int bb = id / 200, n = id - bb * 200;
      int em = et_s[bb][n];
      if (em & 16) {
        if (g == 0) {
          p_s[bb][0][n] = -1e10f;
          p_s[bb][1][n] = -1e10f;
          p_s[bb][2][n] = -1e10f;
          p_s[bb][3][n] = -1e10f;
        }
      } else {
        const float4* kr =
            (const float4*)(k + ((size_t)(b0 + bb) * N_ + n) * D_);
        float4 kb[8];
#pragma unroll
        for (int t = 0; t < 8; ++t) kb[t] = kr[g + 4 * t];
        const int eh0 = (em & 3) * 4;
        const float4* m0 = (const float4*)&ehbuf[bb][eh0 + 0][0];
        const float4* m1 = (const float4*)&ehbuf[bb][eh0 + 1][0];
        const float4* m2 = (const float4*)&ehbuf[bb][eh0 + 2][0];
        const float4* m3 = (const float4*)&ehbuf[bb][eh0 + 3][0];
        float a0 = 0.f, a1 = 0.f, a2 = 0.f, a3 = 0.f;
#pragma unroll
        for (int t = 0; t < 8; ++t) {
          int c = g + 4 * t;
          float4 x0 = m0[c];
          a0 += kb[t].x * x0.x + kb[t].y * x0.y + kb[t].z * x0.z +
                kb[t].w * x0.w;
          float4 x1 = m1[c];
          a1 += kb[t].x * x1.x + kb[t].y * x1.y + kb[t].z * x1.z +
                kb[t].w * x1.w;
          float4 x2 = m2[c];
          a2 += kb[t].x * x2.x + kb[t].y * x2.y + kb[t].z * x2.z +
                kb[t].w * x2.w;
          float4 x3 = m3[c];
          a3 += kb[t].x * x3.x + kb[t].y * x3.y + kb[t].z * x3.z +
                kb[t].w * x3.w;
        }
        a0 += __shfl_xor(a0, 1);
        a0 += __shfl_xor(a0, 2);
        a1 += __shfl_xor(a1, 1);
        a1 += __shfl_xor(a1, 2);
        a2 += __shfl_xor(a2, 1);
        a2 += __shfl_xor(a2, 2);
        a3 += __shfl_xor(a3, 1);
        a3 += __shfl_xor(a3, 2);
        if (g == 0) {
          p_s[bb][0][n] = a0;
          p_s[bb][1][n] = a1;
          p_s[bb][2][n] = a2;
          p_s[bb][3][n] = a3;
        }
      }
    }
  }
  __syncthreads();

  // ---------------- Phase 4: softmax; wave task t=(bb,h) ----------------
#pragma unroll
  for (int it = 0; it < 2; ++it) {
    int t = w * 2 + it, bb = t >> 2, h = t & 3;
    float mx = -1e30f;
    for (int n = l; n < N_; n += 64) mx = fmaxf(mx, p_s[bb][h][n]);
#pragma unroll
    for (int o = 32; o; o >>= 1) mx = fmaxf(mx, __shfl_xor(mx, o));
    float sum = 0.f;
    for (int n = l; n < N_; n += 64) {
      float e = __expf(p_s[bb][h][n] - mx);
      p_s[bb][h][n] = e;
      sum += e;
    }
#pragma unroll
    for (int o = 32; o; o >>= 1) sum += __shfl_xor(sum, o);
    float inv = 1.f / sum;
    for (int n = l; n < N_; n += 64) {
      float pp = p_s[bb][h][n] * inv;
      p_s[bb][h][n] = pp;
      attn_out[((size_t)h * B_ + (b0 + bb)) * N_ + n] = pp;
    }
  }
  __syncthreads();

  // ---------------- Phase 5: PV; wave=(bb, e-pair); float2 full-row loads ----------------
  {
    const int bb = w >> 1, ehalf = w & 1;
    const float2* vb2 = (const float2*)(v + (size_t)(b0 + bb) * N_ * D_);
#pragma unroll
    for (int ee = 0; ee < 2; ++ee) {
      const int e = ehalf * 2 + ee;
      const int j0 = goff_s[bb][e], j1 = goff_s[bb][e + 1];
      float2 acc0 = {0.f, 0.f}, acc1 = {0.f, 0.f};
      float2 acc2 = {0.f, 0.f}, acc3 = {0.f, 0.f};
      for (int j = j0; j < j1; j += 8) {
        int nn[8];
        float okf[8];
        float2 vv[8];
#pragma unroll
        for (int u = 0; u < 8; ++u) {
          bool ok = (j + u) < j1;
          nn[u] = ok ? (int)perm_s[bb][j + u] : (int)perm_s[bb][j0];
          okf[u] = ok ? 1.f : 0.f;
        }
#pragma unroll
        for (int u = 0; u < 8; ++u) vv[u] = vb2[nn[u] * 64 + l];
#pragma unroll
        for (int u = 0; u < 8; ++u) {
          float p0 = p_s[bb][0][nn[u]] * okf[u];
          acc0.x = fmaf(p0, vv[u].x, acc0.x);
          acc0.y = fmaf(p0, vv[u].y, acc0.y);
          float p1 = p_s[bb][1][nn[u]] * okf[u];
          acc1.x = fmaf(p1, vv[u].x, acc1.x);
          acc1.y = fmaf(p1, vv[u].y, acc1.y);
          float p2 = p_s[bb][2][nn[u]] * okf[u];
          acc2.x = fmaf(p2, vv[u].x, acc2.x);
          acc2.y = fmaf(p2, vv[u].y, acc2.y);
          float p3 = p_s[bb][3][nn[u]] * okf[u];
          acc3.x = fmaf(p3, vv[u].x, acc3.x);
          acc3.y = fmaf(p3, vv[u].y, acc3.y);
        }
      }
      ((float2*)&ehbuf[bb][e * 4 + 0][0])[l] = acc0;
      ((float2*)&ehbuf[bb][e * 4 + 1][0])[l] = acc1;
      ((float2*)&ehbuf[bb][e * 4 + 2][0])[l] = acc2;
      ((float2*)&ehbuf[bb][e * 4 + 3][0])[l] = acc3;
    }
  }
  __syncthreads();

  // ---------------- Phase 6: Wv contract; loads shared x4, 8-deep ----------------
  {
    int row = grp, hh = row >> 5;
    float acc[4] = {0.f, 0.f, 0.f, 0.f};
#pragma unroll
    for (int e = 0; e < 4; ++e) {
      const float4* wr = (const float4*)(Wv + ((size_t)e * 128 + row) * 128);
      float4 wb[8];
#pragma unroll
      for (int t = 0; t < 8; ++t) wb[t] = wr[g + 4 * t];
#pragma unroll
      for (int t = 0; t < 8; ++t) {
        int c = g + 4 * t;
#pragma unroll
        for (int bb = 0; bb < 4; ++bb) {
          float4 sv = ((const float4*)&ehbuf[bb][e * 4 + hh][0])[c];
          acc[bb] += wb[t].x * sv.x + wb[t].y * sv.y + wb[t].z * sv.z +
                     wb[t].w * sv.w;
        }
      }
    }
#pragma unroll
    for (int bb = 0; bb < 4; ++bb) {
      acc[bb] += __shfl_xor(acc[bb], 1);
      acc[bb] += __shfl_xor(acc[bb], 2);
    }
    if (g == 0) {
#pragma unroll
      for (int bb = 0; bb < 4; ++bb) part_s[bb][row] = acc[bb];
    }
  }
  __syncthreads();

  // ---------------- Phase 7: FC (one (bb,j) per thread) + residual + LN ----------------
  {
    const int bb = tid >> 7, j = tid & 127;
    const float* wf = W_fc + ((size_t)u_s[bb] * 128) * 128 + j;
    float acc = 0.f;
    for (int r0 = 0; r0 < 128; r0 += 8) {
      float wv[8], ov[8];
#pragma unroll
      for (int u = 0; u < 8; ++u) wv[u] = wf[(r0 + u) * 128];
#pragma unroll
      for (int u = 0; u < 8; ++u) ov[u] = part_s[bb][r0 + u];
#pragma unroll
      for (int u = 0; u < 8; ++u) acc = fmaf(ov[u], wv[u], acc);
    }
    float x = acc + b_fc[u_s[bb] * 128 + j] + q_s[bb][j];

    float s1 = x, s2 = x * x;
#pragma unroll
    for (int o = 32; o; o >>= 1) {
      s1 += __shfl_xor(s1, o);
      s2 += __shfl_xor(s2, o);
    }
    const int half = (tid >> 6) & 1;
    if (l == 0) {
      red_s[bb][half] = s1;
      red_s[bb][4 + half] = s2;
    }
    __syncthreads();
    float t1 = red_s[bb][0] + red_s[bb][1];
    float t2 = red_s[bb][4] + red_s[bb][5];
    float mu = t1 * (1.f / 128.f);
    float var = t2 * (1.f / 128.f) - mu * mu;
    float yv = (x - mu) * rsqrtf(var + 1e-5f) * ln_gamma[j] + ln_beta[j];
    y_out[(size_t)(b0 + bb) * 128 + j] = yv;
  }
}

extern "C" void kernel_launch(void* const* d_in, const int* in_sizes, int n_in,
                              void* d_out, int out_size, void* d_ws,
                              size_t ws_size, hipStream_t stream) {
  const float* q = (const float*)d_in[0];
  const float* k = (const float*)d_in[1];
  const float* v = (const float*)d_in[2];
  const float* Wq = (const float*)d_in[3];
  const float* Wk = (const float*)d_in[4];
  const float* Wv = (const float*)d_in[5];
  const float* rp = (const float*)d_in[6];
  const float* Wf = (const float*)d_in[7];
  const float* bf = (const float*)d_in[8];
  const float* g = (const float*)d_in[9];
  const float* be = (const float*)d_in[10];
  const int* et = (const int*)d_in[11];
  const int* ut = (const int*)d_in[12];
  const void* mask = d_in[13];

  float* y = (float*)d_out;
  float* attn = y + (size_t)B_ * D_;

  fused_mha_kernel<<<B_ / 4, 512, 0, stream>>>(q, k, v, Wq, Wk, Wv, rp, Wf, bf,
                                               g, be, et, ut, mask, y, attn);
}